// Round 5
// baseline (4748.993 us; speedup 1.0000x reference)
//
#include <hip/hip_runtime.h>
#include <stdint.h>

#define NPTS   32768
#define NBATCH 8
#define NFPS   512
#define NGRP   32
#define BIGF   1e10f
#define R2F    0.04f
#define CAP    512
#define QPB    4      // ball-query centroids per block

__device__ __forceinline__ unsigned long long shfl_xor_u64(unsigned long long v, int off) {
    unsigned lo = (unsigned)v, hi = (unsigned)(v >> 32);
    lo = __shfl_xor(lo, off, 64);
    hi = __shfl_xor(hi, off, 64);
    return ((unsigned long long)hi << 32) | lo;
}

// ---------------------------------------------------------------------------
// FPS: one block per batch, 512 threads, 64 points/thread (p = t*64 + k).
// R1-R4 LESSON: every 1024-thread variant was pinned to 64 VGPRs and spilled
// (R4's WRITE_SIZE showed the 1 MB dist[32] scratch leak). This round: 8-wave
// block + waves_per_eu(2,2) -> 256-VGPR budget (m69 occupancy step), holding
// xr[64], yr[64], dist[64] (~222 regs incl. temps) with NO spills.
// z streams per-iter from dense zt scratch (written once from self-owned
// lanes -- no barrier needed; 128 KB/iter/CU from L2 ~0.9us, overlaps VALU).
// Argmax fused: strict '>' keeps first occurrence; block reduce on u64 key
// (distbits<<32 | ~idx) -> max dist, ties -> min index. Single barrier per
// iter via double-buffered redK. Distance math bit-exact vs reference:
// contract off, (dx^2+dy^2)+dz^2, fminf accumulate.
// ---------------------------------------------------------------------------
__global__ __launch_bounds__(512)
__attribute__((amdgpu_waves_per_eu(2, 2)))
void fps_kernel(
    const float* __restrict__ xyz,
    const int* __restrict__ finit,
    int* __restrict__ cidx,        // [NBATCH][NFPS]
    float* __restrict__ zt)        // [NBATCH][NPTS] dense z scratch
{
#pragma clang fp contract(off)
    const int b = blockIdx.x;
    const int t = threadIdx.x;
    const float* __restrict__ base = xyz + (size_t)b * (NPTS * 3);
    float* __restrict__ ztb = zt + (size_t)b * NPTS;
    // thread t owns points p = t*64 .. t*64+63 -> floats [t*192, t*192+192)
    const float4* __restrict__ b4 =
        reinterpret_cast<const float4*>(base) + (size_t)t * 48;
    float4* __restrict__ ztb4 =
        reinterpret_cast<float4*>(ztb) + (size_t)t * 16;

    __shared__ unsigned long long redK[2][8];

    float xr[64], yr[64], dist[64];
#pragma unroll
    for (int j = 0; j < 16; ++j) {
        const float4 q0 = b4[3 * j + 0];
        const float4 q1 = b4[3 * j + 1];
        const float4 q2 = b4[3 * j + 2];
        xr[4 * j + 0] = q0.x;  yr[4 * j + 0] = q0.y;
        xr[4 * j + 1] = q0.w;  yr[4 * j + 1] = q1.x;
        xr[4 * j + 2] = q1.z;  yr[4 * j + 2] = q1.w;
        xr[4 * j + 3] = q2.y;  yr[4 * j + 3] = q2.z;
        ztb4[j] = make_float4(q0.z, q1.y, q2.x, q2.w);
        dist[4 * j + 0] = BIGF; dist[4 * j + 1] = BIGF;
        dist[4 * j + 2] = BIGF; dist[4 * j + 3] = BIGF;
    }

    int far = finit[b];
    const int wid  = t >> 6;       // 0..7
    const int lane = t & 63;
    int parity = 0;

    const float4* __restrict__ z4 =
        reinterpret_cast<const float4*>(ztb) + (size_t)t * 16;

    for (int it = 0; it < NFPS; ++it) {
        if (t == 0) cidx[b * NFPS + it] = far;   // record BEFORE update (scan semantics)
        const float cx = base[3 * far + 0];
        const float cy = base[3 * far + 1];
        const float cz = base[3 * far + 2];

        float vmax = -1.0f;
        int   amax = 0;

#define PROC(K, PZ)                                           \
        {                                                     \
            const int k_ = (K);                               \
            float dx = xr[k_] - cx;                           \
            float dy = yr[k_] - cy;                           \
            float dz = (PZ) - cz;                             \
            float d  = dx * dx + dy * dy;                     \
            d = d + dz * dz;                                  \
            float dk = fminf(dist[k_], d);                    \
            dist[k_] = dk;                                    \
            if (dk > vmax) { vmax = dk; amax = t * 64 + k_; } \
        }

#pragma unroll
        for (int j = 0; j < 16; ++j) {
            const float4 zq = z4[j];
            PROC(4 * j + 0, zq.x);
            PROC(4 * j + 1, zq.y);
            PROC(4 * j + 2, zq.z);
            PROC(4 * j + 3, zq.w);
        }
#undef PROC

        // u64 key: high=distbits (>=0 so bit order == float order), low=~idx
        unsigned long long key =
            ((unsigned long long)__float_as_uint(vmax) << 32)
            | (unsigned)(0xFFFFFFFFu - (unsigned)amax);
#pragma unroll
        for (int off = 32; off >= 1; off >>= 1) {
            unsigned long long o = shfl_xor_u64(key, off);
            key = (o > key) ? o : key;
        }
        if (lane == 0) redK[parity][wid] = key;
        __syncthreads();
        // every thread serially reduces the 8 wave keys (LDS broadcast).
        // next iteration's leader-writes target the OTHER buffer -> no
        // second barrier needed.
        unsigned long long best = redK[parity][0];
#pragma unroll
        for (int w = 1; w < 8; ++w) {
            unsigned long long o = redK[parity][w];
            best = (o > best) ? o : best;
        }
        far = (int)(0xFFFFFFFFu - (unsigned)(best & 0xFFFFFFFFull));
        parity ^= 1;
    }
}

// ---------------------------------------------------------------------------
// Ball query + grouping: QPB centroids per block (amortize the xyz stream).
// Per point: 1 load, QPB distance tests -> append to per-centroid LDS list.
// Rank-select done one wave per centroid. Fill = lowest-index out-of-radius
// points (always within indices 0..62) via one 64-lane ballot per centroid.
// ---------------------------------------------------------------------------
__global__ __launch_bounds__(256) void ballq_kernel(
    const float* __restrict__ xyz,
    const int* __restrict__ cidx,
    float* __restrict__ out0,      // [B][S][33][3]
    float* __restrict__ out1)      // [B][S][3]
{
#pragma clang fp contract(off)
    const int blk0 = blockIdx.x * QPB;   // first global centroid (b*NFPS+s)
    const int b    = blk0 >> 9;          // QPB divides NFPS -> same batch
    const int t    = threadIdx.x;
    const float* __restrict__ base = xyz + (size_t)b * (NPTS * 3);

    __shared__ unsigned long long list[QPB][CAP];
    __shared__ int scnt[QPB];
    __shared__ unsigned long long mask0[QPB];
    __shared__ int selIdx[QPB][NGRP];

    if (t < QPB) scnt[t] = 0;

    float cxs[QPB], cys[QPB], czs[QPB];
#pragma unroll
    for (int q = 0; q < QPB; ++q) {
        const int ci = cidx[blk0 + q];
        cxs[q] = base[3 * ci + 0];
        cys[q] = base[3 * ci + 1];
        czs[q] = base[3 * ci + 2];
    }
    __syncthreads();

    // in-ball masks for the first 64 indices (fill candidates); wave 0 only
    if (t < 64) {
        const float px = base[3 * t + 0];
        const float py = base[3 * t + 1];
        const float pz = base[3 * t + 2];
#pragma unroll
        for (int q = 0; q < QPB; ++q) {
            float dx = px - cxs[q];
            float dy = py - cys[q];
            float dz = pz - czs[q];
            float d  = dx * dx + dy * dy;
            d = d + dz * dz;
            unsigned long long mk = __ballot(d <= R2F);
            if (t == 0) mask0[q] = mk;
        }
    }

    // scan all points once; test against all QPB centroids
    for (int k = 0; k < NPTS / 256; ++k) {
        const int p = k * 256 + t;
        const float px = base[3 * p + 0];
        const float py = base[3 * p + 1];
        const float pz = base[3 * p + 2];
#pragma unroll
        for (int q = 0; q < QPB; ++q) {
            float dx = px - cxs[q];
            float dy = py - cys[q];
            float dz = pz - czs[q];
            float d  = dx * dx + dy * dy;
            d = d + dz * dz;
            if (d <= R2F) {
                int pos = atomicAdd(&scnt[q], 1);
                if (pos < CAP)
                    list[q][pos] = (((unsigned long long)__float_as_uint(d)) << 32)
                                   | (unsigned)p;
            }
        }
    }
    __syncthreads();

    // rank-based selection, one wave per centroid:
    // key's rank == #smaller keys (keys unique via idx)
    {
        const int q    = t >> 6;     // wave id 0..3
        const int lane = t & 63;
        const int m = min(scnt[q], CAP);
        for (int j = lane; j < m; j += 64) {
            const unsigned long long kj = list[q][j];
            int rank = 0;
            for (int i = 0; i < m; ++i) rank += (list[q][i] < kj) ? 1 : 0;
            if (rank < NGRP) selIdx[q][rank] = (int)(kj & 0xffffffffu);
        }
    }
    __syncthreads();

    if (t < 33 * QPB) {
        const int q    = t / 33;
        const int slot = t % 33;
        const int sg   = blk0 + q;
        const float cx = cxs[q], cy = cys[q], cz = czs[q];
        const size_t o0 = (size_t)sg * 33 * 3;
        if (slot == 32) {
            out0[o0 + 0] = cx; out0[o0 + 1] = cy; out0[o0 + 2] = cz;
            const size_t o1 = (size_t)sg * 3;
            out1[o1 + 0] = cx; out1[o1 + 1] = cy; out1[o1 + 2] = cz;
        } else {
            const int m = min(scnt[q], CAP);
            const int K = min(m, NGRP);
            int idx;
            if (slot < K) {
                idx = selIdx[q][slot];
            } else {
                // (slot-K+1)-th zero bit of mask0 = next out-of-radius index
                unsigned long long zeros = ~mask0[q];
                const int need = slot - K;
                for (int z = 0; z < need; ++z) zeros &= zeros - 1;
                idx = __builtin_ctzll(zeros);
            }
            const float px = base[3 * idx + 0];
            const float py = base[3 * idx + 1];
            const float pz = base[3 * idx + 2];
            out0[o0 + (size_t)(1 + slot) * 3 + 0] = px - cx;
            out0[o0 + (size_t)(1 + slot) * 3 + 1] = py - cy;
            out0[o0 + (size_t)(1 + slot) * 3 + 2] = pz - cz;
        }
    }
}

extern "C" void kernel_launch(void* const* d_in, const int* in_sizes, int n_in,
                              void* d_out, int out_size, void* d_ws, size_t ws_size,
                              hipStream_t stream) {
    const float* xyz   = (const float*)d_in[0];
    const int*   finit = (const int*)d_in[1];
    float* out0 = (float*)d_out;
    float* out1 = out0 + (size_t)NBATCH * NFPS * 33 * 3;

    int*   cidx = (int*)d_ws;                                   // 16 KB
    float* zt   = (float*)((char*)d_ws + (size_t)NBATCH * NFPS * sizeof(int));
    // ws_size >= 1.06 MB proven in R1-R3 (zt path ran there)

    fps_kernel<<<NBATCH, 512, 0, stream>>>(xyz, finit, cidx, zt);
    ballq_kernel<<<(NBATCH * NFPS) / QPB, 256, 0, stream>>>(xyz, cidx, out0, out1);
}

// Round 6
// 4110.627 us; speedup vs baseline: 1.1553x; 1.1553x over previous
//
#include <hip/hip_runtime.h>
#include <stdint.h>

#define NPTS   32768
#define NBATCH 8
#define NFPS   512
#define NGRP   32
#define BIGF   1e10f
#define R2F    0.04f
#define CAP    512
#define QPB    4      // ball-query centroids per block

__device__ __forceinline__ unsigned long long shfl_xor_u64(unsigned long long v, int off) {
    unsigned lo = (unsigned)v, hi = (unsigned)(v >> 32);
    lo = __shfl_xor(lo, off, 64);
    hi = __shfl_xor(hi, off, 64);
    return ((unsigned long long)hi << 32) | lo;
}

// ---------------------------------------------------------------------------
// FPS: one block per batch, 512 threads, 64 points/thread (p = t*64 + k).
// R1-R5 UNIFIED DIAGNOSIS: the allocator REMATERIALIZES loads of const
// __restrict__ data instead of keeping them live -- every iteration re-issued
// the xr/yr global loads from the interleaved layout (512 KB/iter L2 stream,
// R5's 9.1us/iter), while computed (non-remat) dist[] was what spilled in
// R1-R4. FIX: inline-asm pin (asm "+v") after the load turns each xr/yr
// value into an opaque non-remat asm result that must hold a VGPR. Budget:
// waves_per_eu(2,2) + amdgpu_num_vgpr(256) -> 2 waves/EU, 256-reg cap;
// demand = xr[64]+yr[64]+dist[64]+~30 temps ~ 222, fits.
// z streams per-iter from dense zt scratch (written once from self-owned
// lanes, no barrier; 128 KB/iter/CU from L2, overlaps VALU).
// Argmax fused: strict '>' keeps first occurrence; block reduce on u64 key
// (distbits<<32 | ~idx) -> max dist, ties -> min index. Single barrier per
// iter via double-buffered redK. Distance math bit-exact vs reference:
// contract off, (dx^2+dy^2)+dz^2, fminf accumulate.
// ---------------------------------------------------------------------------
__global__
__attribute__((amdgpu_flat_work_group_size(512, 512)))
__attribute__((amdgpu_waves_per_eu(2, 2)))
__attribute__((amdgpu_num_vgpr(256)))
void fps_kernel(
    const float* __restrict__ xyz,
    const int* __restrict__ finit,
    int* __restrict__ cidx,        // [NBATCH][NFPS]
    float* __restrict__ zt)        // [NBATCH][NPTS] dense z scratch
{
#pragma clang fp contract(off)
    const int b = blockIdx.x;
    const int t = threadIdx.x;
    const float* __restrict__ base = xyz + (size_t)b * (NPTS * 3);
    float* __restrict__ ztb = zt + (size_t)b * NPTS;
    // thread t owns points p = t*64 .. t*64+63 -> floats [t*192, t*192+192)
    const float4* __restrict__ b4 =
        reinterpret_cast<const float4*>(base) + (size_t)t * 48;
    float4* __restrict__ ztb4 =
        reinterpret_cast<float4*>(ztb) + (size_t)t * 16;

    __shared__ unsigned long long redK[2][8];

    float xr[64], yr[64], dist[64];
#pragma unroll
    for (int j = 0; j < 16; ++j) {
        const float4 q0 = b4[3 * j + 0];
        const float4 q1 = b4[3 * j + 1];
        const float4 q2 = b4[3 * j + 2];
        xr[4 * j + 0] = q0.x;  yr[4 * j + 0] = q0.y;
        xr[4 * j + 1] = q0.w;  yr[4 * j + 1] = q1.x;
        xr[4 * j + 2] = q1.z;  yr[4 * j + 2] = q1.w;
        xr[4 * j + 3] = q2.y;  yr[4 * j + 3] = q2.z;
        ztb4[j] = make_float4(q0.z, q1.y, q2.x, q2.w);
        dist[4 * j + 0] = BIGF; dist[4 * j + 1] = BIGF;
        dist[4 * j + 2] = BIGF; dist[4 * j + 3] = BIGF;
    }
    // Opaque pin: forces xr/yr into live VGPRs; the values become asm
    // results, which the allocator cannot rematerialize from global loads.
#pragma unroll
    for (int k = 0; k < 64; ++k) {
        asm("" : "+v"(xr[k]), "+v"(yr[k]));
    }

    int far = finit[b];
    const int wid  = t >> 6;       // 0..7
    const int lane = t & 63;
    int parity = 0;

    const float4* __restrict__ z4 =
        reinterpret_cast<const float4*>(ztb) + (size_t)t * 16;

    for (int it = 0; it < NFPS; ++it) {
        if (t == 0) cidx[b * NFPS + it] = far;   // record BEFORE update (scan semantics)
        const float cx = base[3 * far + 0];
        const float cy = base[3 * far + 1];
        const float cz = base[3 * far + 2];

        float vmax = -1.0f;
        int   amax = 0;

#define PROC(K, PZ)                                           \
        {                                                     \
            const int k_ = (K);                               \
            float dx = xr[k_] - cx;                           \
            float dy = yr[k_] - cy;                           \
            float dz = (PZ) - cz;                             \
            float d  = dx * dx + dy * dy;                     \
            d = d + dz * dz;                                  \
            float dk = fminf(dist[k_], d);                    \
            dist[k_] = dk;                                    \
            if (dk > vmax) { vmax = dk; amax = t * 64 + k_; } \
        }

#pragma unroll
        for (int j = 0; j < 16; ++j) {
            const float4 zq = z4[j];
            PROC(4 * j + 0, zq.x);
            PROC(4 * j + 1, zq.y);
            PROC(4 * j + 2, zq.z);
            PROC(4 * j + 3, zq.w);
        }
#undef PROC

        // u64 key: high=distbits (>=0 so bit order == float order), low=~idx
        unsigned long long key =
            ((unsigned long long)__float_as_uint(vmax) << 32)
            | (unsigned)(0xFFFFFFFFu - (unsigned)amax);
#pragma unroll
        for (int off = 32; off >= 1; off >>= 1) {
            unsigned long long o = shfl_xor_u64(key, off);
            key = (o > key) ? o : key;
        }
        if (lane == 0) redK[parity][wid] = key;
        __syncthreads();
        // every thread serially reduces the 8 wave keys (LDS broadcast).
        // next iteration's leader-writes target the OTHER buffer -> no
        // second barrier needed.
        unsigned long long best = redK[parity][0];
#pragma unroll
        for (int w = 1; w < 8; ++w) {
            unsigned long long o = redK[parity][w];
            best = (o > best) ? o : best;
        }
        far = (int)(0xFFFFFFFFu - (unsigned)(best & 0xFFFFFFFFull));
        parity ^= 1;
    }
}

// ---------------------------------------------------------------------------
// Ball query + grouping: QPB centroids per block (amortize the xyz stream).
// Per point: 1 load, QPB distance tests -> append to per-centroid LDS list.
// Rank-select one wave per centroid. Fill = lowest-index out-of-radius
// points (always within indices 0..62) via one 64-lane ballot per centroid.
// (unchanged from R5: median ~90us; the 30ms entry was a rocprof-replay
// outlier, same artifact as R1-R4's 48ms fps entries.)
// ---------------------------------------------------------------------------
__global__ __launch_bounds__(256) void ballq_kernel(
    const float* __restrict__ xyz,
    const int* __restrict__ cidx,
    float* __restrict__ out0,      // [B][S][33][3]
    float* __restrict__ out1)      // [B][S][3]
{
#pragma clang fp contract(off)
    const int blk0 = blockIdx.x * QPB;   // first global centroid (b*NFPS+s)
    const int b    = blk0 >> 9;          // QPB divides NFPS -> same batch
    const int t    = threadIdx.x;
    const float* __restrict__ base = xyz + (size_t)b * (NPTS * 3);

    __shared__ unsigned long long list[QPB][CAP];
    __shared__ int scnt[QPB];
    __shared__ unsigned long long mask0[QPB];
    __shared__ int selIdx[QPB][NGRP];

    if (t < QPB) scnt[t] = 0;

    float cxs[QPB], cys[QPB], czs[QPB];
#pragma unroll
    for (int q = 0; q < QPB; ++q) {
        const int ci = cidx[blk0 + q];
        cxs[q] = base[3 * ci + 0];
        cys[q] = base[3 * ci + 1];
        czs[q] = base[3 * ci + 2];
    }
    __syncthreads();

    // in-ball masks for the first 64 indices (fill candidates); wave 0 only
    if (t < 64) {
        const float px = base[3 * t + 0];
        const float py = base[3 * t + 1];
        const float pz = base[3 * t + 2];
#pragma unroll
        for (int q = 0; q < QPB; ++q) {
            float dx = px - cxs[q];
            float dy = py - cys[q];
            float dz = pz - czs[q];
            float d  = dx * dx + dy * dy;
            d = d + dz * dz;
            unsigned long long mk = __ballot(d <= R2F);
            if (t == 0) mask0[q] = mk;
        }
    }

    // scan all points once; test against all QPB centroids
    for (int k = 0; k < NPTS / 256; ++k) {
        const int p = k * 256 + t;
        const float px = base[3 * p + 0];
        const float py = base[3 * p + 1];
        const float pz = base[3 * p + 2];
#pragma unroll
        for (int q = 0; q < QPB; ++q) {
            float dx = px - cxs[q];
            float dy = py - cys[q];
            float dz = pz - czs[q];
            float d  = dx * dx + dy * dy;
            d = d + dz * dz;
            if (d <= R2F) {
                int pos = atomicAdd(&scnt[q], 1);
                if (pos < CAP)
                    list[q][pos] = (((unsigned long long)__float_as_uint(d)) << 32)
                                   | (unsigned)p;
            }
        }
    }
    __syncthreads();

    // rank-based selection, one wave per centroid:
    // key's rank == #smaller keys (keys unique via idx)
    {
        const int q    = t >> 6;     // wave id 0..3
        const int lane = t & 63;
        const int m = min(scnt[q], CAP);
        for (int j = lane; j < m; j += 64) {
            const unsigned long long kj = list[q][j];
            int rank = 0;
            for (int i = 0; i < m; ++i) rank += (list[q][i] < kj) ? 1 : 0;
            if (rank < NGRP) selIdx[q][rank] = (int)(kj & 0xffffffffu);
        }
    }
    __syncthreads();

    if (t < 33 * QPB) {
        const int q    = t / 33;
        const int slot = t % 33;
        const int sg   = blk0 + q;
        const float cx = cxs[q], cy = cys[q], cz = czs[q];
        const size_t o0 = (size_t)sg * 33 * 3;
        if (slot == 32) {
            out0[o0 + 0] = cx; out0[o0 + 1] = cy; out0[o0 + 2] = cz;
            const size_t o1 = (size_t)sg * 3;
            out1[o1 + 0] = cx; out1[o1 + 1] = cy; out1[o1 + 2] = cz;
        } else {
            const int m = min(scnt[q], CAP);
            const int K = min(m, NGRP);
            int idx;
            if (slot < K) {
                idx = selIdx[q][slot];
            } else {
                // (slot-K+1)-th zero bit of mask0 = next out-of-radius index
                unsigned long long zeros = ~mask0[q];
                const int need = slot - K;
                for (int z = 0; z < need; ++z) zeros &= zeros - 1;
                idx = __builtin_ctzll(zeros);
            }
            const float px = base[3 * idx + 0];
            const float py = base[3 * idx + 1];
            const float pz = base[3 * idx + 2];
            out0[o0 + (size_t)(1 + slot) * 3 + 0] = px - cx;
            out0[o0 + (size_t)(1 + slot) * 3 + 1] = py - cy;
            out0[o0 + (size_t)(1 + slot) * 3 + 2] = pz - cz;
        }
    }
}

extern "C" void kernel_launch(void* const* d_in, const int* in_sizes, int n_in,
                              void* d_out, int out_size, void* d_ws, size_t ws_size,
                              hipStream_t stream) {
    const float* xyz   = (const float*)d_in[0];
    const int*   finit = (const int*)d_in[1];
    float* out0 = (float*)d_out;
    float* out1 = out0 + (size_t)NBATCH * NFPS * 33 * 3;

    int*   cidx = (int*)d_ws;                                   // 16 KB
    float* zt   = (float*)((char*)d_ws + (size_t)NBATCH * NFPS * sizeof(int));
    // ws_size >= 1.07 MB proven in R1-R3 (zt path ran there)

    fps_kernel<<<NBATCH, 512, 0, stream>>>(xyz, finit, cidx, zt);
    ballq_kernel<<<(NBATCH * NFPS) / QPB, 256, 0, stream>>>(xyz, cidx, out0, out1);
}